// Round 2
// baseline (2688.249 us; speedup 1.0000x reference)
//
#include <hip/hip_runtime.h>
#include <math.h>

// Problem dims
#define B_ 4
#define L_ 512
#define MROWS (B_ * L_)          // 2048
#define D_MODEL 384
#define N_LAYER 4
#define D_INNER 768
#define N_STATE 16
#define DT_RANK 24
#define D_CONV 4
#define VOCAB 1544
#define FEAT 1536
#define XPROJ_N (DT_RANK + 2 * N_STATE)   // 56

__device__ __forceinline__ float softplus_f(float x) { return x > 20.f ? x : log1pf(expf(x)); }
__device__ __forceinline__ float silu_f(float x) { return x / (1.f + expf(-x)); }

// ---------------------------------------------------------------------------
// Tiled GEMM: C[m,n] = sum_k A[m,k] * W[n,k]  (A: MxK lda, W: NxK row-major)
// EPI: 0 none, 1 +bias, 2 softplus(x+bias), 3 +res (residual, ldc layout)
// ---------------------------------------------------------------------------
#define BM 64
#define BN 64
#define BK 16

template <int EPI>
__global__ __launch_bounds__(256) void gemm_bt(
    const float* __restrict__ A, const float* __restrict__ W,
    const float* __restrict__ bias, const float* __restrict__ res,
    float* __restrict__ C, int M, int N, int K, int lda, int ldc)
{
    __shared__ float As[BK][BM + 1];
    __shared__ float Ws[BK][BN + 1];
    const int t  = threadIdx.x;
    const int tx = t & 15;        // n-dim
    const int ty = t >> 4;        // m-dim
    const int m0 = blockIdx.y * BM;
    const int n0 = blockIdx.x * BN;

    float acc[4][4] = {};

    for (int k0 = 0; k0 < K; k0 += BK) {
#pragma unroll
        for (int c = 0; c < 4; ++c) {
            int lin = t + c * 256;
            int r   = lin >> 4;
            int col = lin & 15;
            int gk  = k0 + col;
            int gm  = m0 + r;
            float va = 0.f;
            if (gm < M && gk < K) va = A[(size_t)gm * lda + gk];
            As[col][r] = va;
            int gn = n0 + r;
            float vw = 0.f;
            if (gn < N && gk < K) vw = W[(size_t)gn * K + gk];
            Ws[col][r] = vw;
        }
        __syncthreads();
#pragma unroll
        for (int kk = 0; kk < BK; ++kk) {
            float a[4], b[4];
#pragma unroll
            for (int i = 0; i < 4; ++i) a[i] = As[kk][ty * 4 + i];
#pragma unroll
            for (int j = 0; j < 4; ++j) b[j] = Ws[kk][tx * 4 + j];
#pragma unroll
            for (int i = 0; i < 4; ++i)
#pragma unroll
                for (int j = 0; j < 4; ++j) acc[i][j] += a[i] * b[j];
        }
        __syncthreads();
    }

#pragma unroll
    for (int i = 0; i < 4; ++i) {
        int gm = m0 + ty * 4 + i;
        if (gm >= M) continue;
#pragma unroll
        for (int j = 0; j < 4; ++j) {
            int gn = n0 + tx * 4 + j;
            if (gn >= N) continue;
            float v = acc[i][j];
            if (EPI == 1 || EPI == 2) v += bias[gn];
            if (EPI == 2) v = softplus_f(v);
            if (EPI == 3) v += res[(size_t)gm * ldc + gn];
            C[(size_t)gm * ldc + gn] = v;
        }
    }
}

// ---------------------------------------------------------------------------
// RMSNorm: out[m,:] = x[m,:] * rsqrt(mean(x^2)+1e-5) * w  (D = 384)
// ---------------------------------------------------------------------------
__global__ __launch_bounds__(128) void rmsnorm_k(
    const float* __restrict__ x, const float* __restrict__ w,
    float* __restrict__ out, int D)
{
    const int m = blockIdx.x;
    const float* xr = x + (size_t)m * D;
    float s = 0.f;
    for (int i = threadIdx.x; i < D; i += 128) { float v = xr[i]; s += v * v; }
#pragma unroll
    for (int off = 32; off > 0; off >>= 1) s += __shfl_down(s, off, 64);
    __shared__ float red[2];
    if ((threadIdx.x & 63) == 0) red[threadIdx.x >> 6] = s;
    __syncthreads();
    float tot = red[0] + red[1];
    float scale = rsqrtf(tot / (float)D + 1e-5f);
    for (int i = threadIdx.x; i < D; i += 128)
        out[(size_t)m * D + i] = xr[i] * scale * w[i];
}

// ---------------------------------------------------------------------------
// Depthwise causal conv (width 4) + bias + SiLU.
// xz: [M, 2*D_INNER], take first D_INNER cols. u: [M, D_INNER]
// ---------------------------------------------------------------------------
__global__ __launch_bounds__(256) void conv_silu_k(
    const float* __restrict__ xz, const float* __restrict__ w,
    const float* __restrict__ cb, float* __restrict__ u)
{
    int idx = blockIdx.x * 256 + threadIdx.x;
    if (idx >= MROWS * D_INNER) return;
    int d = idx % D_INNER;
    int m = idx / D_INNER;
    int b = m / L_, l = m % L_;
    float acc = cb[d];
#pragma unroll
    for (int t = 0; t < D_CONV; ++t) {
        int ll = l - (D_CONV - 1) + t;
        if (ll >= 0)
            acc += xz[(size_t)(b * L_ + ll) * (2 * D_INNER) + d] * w[d * D_CONV + t];
    }
    u[idx] = silu_f(acc);
}

// ---------------------------------------------------------------------------
// Selective scan. Block = 256 threads = 16 d-channels x 16 states.
// grid = B_ * (D_INNER/16). xdbl: [M,56] with B at col 24, C at col 40.
// ---------------------------------------------------------------------------
__global__ __launch_bounds__(256) void scan_k(
    const float* __restrict__ delta, const float* __restrict__ u,
    const float* __restrict__ xdbl, const float* __restrict__ A_log,
    const float* __restrict__ Dp, float* __restrict__ y)
{
    const int t  = threadIdx.x;
    const int n  = t & 15;
    const int dl = t >> 4;
    const int b  = blockIdx.x / (D_INNER / 16);
    const int dg = blockIdx.x % (D_INNER / 16);
    const int d  = dg * 16 + dl;

    const float Av = -expf(A_log[d * N_STATE + n]);
    const float Dd = Dp[d];
    float h = 0.f;

    for (int l = 0; l < L_; ++l) {
        size_t m = (size_t)b * L_ + l;
        float dv = delta[m * D_INNER + d];
        float uv = u[m * D_INNER + d];
        float Bv = xdbl[m * XPROJ_N + DT_RANK + n];
        float Cv = xdbl[m * XPROJ_N + DT_RANK + N_STATE + n];
        h = __expf(dv * Av) * h + dv * uv * Bv;
        float p = h * Cv;
        p += __shfl_xor(p, 1, 16);
        p += __shfl_xor(p, 2, 16);
        p += __shfl_xor(p, 4, 16);
        p += __shfl_xor(p, 8, 16);
        if (n == 0) y[m * D_INNER + d] = p + uv * Dd;
    }
}

// ---------------------------------------------------------------------------
// y[m,d] *= silu(xz[m, D_INNER + d])
// ---------------------------------------------------------------------------
__global__ __launch_bounds__(256) void gate_k(
    float* __restrict__ y, const float* __restrict__ xz)
{
    int idx = blockIdx.x * 256 + threadIdx.x;
    if (idx >= MROWS * D_INNER) return;
    int d = idx % D_INNER;
    int m = idx / D_INNER;
    float r = xz[(size_t)m * (2 * D_INNER) + D_INNER + d];
    y[idx] *= silu_f(r);
}

// ---------------------------------------------------------------------------
extern "C" void kernel_launch(void* const* d_in, const int* in_sizes, int n_in,
                              void* d_out, int out_size, void* d_ws, size_t ws_size,
                              hipStream_t stream)
{
    const float* input_ids = (const float*)d_in[0];
    const float* fc_W      = (const float*)d_in[1];
    const float* fc_b      = (const float*)d_in[2];
    const float* in_proj_W = (const float*)d_in[3];
    const float* conv_W    = (const float*)d_in[4];
    const float* conv_b    = (const float*)d_in[5];
    const float* x_proj_W  = (const float*)d_in[6];
    const float* dt_proj_W = (const float*)d_in[7];
    const float* dt_proj_b = (const float*)d_in[8];
    const float* A_log     = (const float*)d_in[9];
    const float* Dp        = (const float*)d_in[10];
    const float* out_proj_W= (const float*)d_in[11];
    const float* norm_W    = (const float*)d_in[12];
    const float* normf_W   = (const float*)d_in[13];
    const float* head_W    = (const float*)d_in[14];
    float* out = (float*)d_out;

    // Workspace layout (f32)
    float* ws       = (float*)d_ws;
    float* x_ws     = ws;                                   // M*384
    float* h_ws     = x_ws    + (size_t)MROWS * D_MODEL;    // M*384
    float* xz_ws    = h_ws    + (size_t)MROWS * D_MODEL;    // M*1536
    float* u_ws     = xz_ws   + (size_t)MROWS * 2 * D_INNER;// M*768
    float* xdbl_ws  = u_ws    + (size_t)MROWS * D_INNER;    // M*56
    float* delta_ws = xdbl_ws + (size_t)MROWS * XPROJ_N;    // M*768
    float* y_ws     = delta_ws+ (size_t)MROWS * D_INNER;    // M*768

    const dim3 blk(256);
    const int ew_blocks = (MROWS * D_INNER + 255) / 256;

    // x = input_ids @ fc_W.T + fc_b
    {
        dim3 grid((D_MODEL + BN - 1) / BN, (MROWS + BM - 1) / BM);
        gemm_bt<1><<<grid, blk, 0, stream>>>(
            input_ids, fc_W, fc_b, nullptr, x_ws, MROWS, D_MODEL, VOCAB, VOCAB, D_MODEL);
    }

    for (int i = 0; i < N_LAYER; ++i) {
        // h = rmsnorm(x) * norm_W[i]
        rmsnorm_k<<<MROWS, 128, 0, stream>>>(x_ws, norm_W + i * D_MODEL, h_ws, D_MODEL);
        // xz = h @ in_proj_W[i].T
        {
            dim3 grid((2 * D_INNER + BN - 1) / BN, (MROWS + BM - 1) / BM);
            gemm_bt<0><<<grid, blk, 0, stream>>>(
                h_ws, in_proj_W + (size_t)i * 2 * D_INNER * D_MODEL, nullptr, nullptr,
                xz_ws, MROWS, 2 * D_INNER, D_MODEL, D_MODEL, 2 * D_INNER);
        }
        // u = silu(conv(xz[:, :768]) + conv_b)
        conv_silu_k<<<ew_blocks, blk, 0, stream>>>(
            xz_ws, conv_W + (size_t)i * D_INNER * D_CONV, conv_b + i * D_INNER, u_ws);
        // x_dbl = u @ x_proj_W[i].T
        {
            dim3 grid((XPROJ_N + BN - 1) / BN, (MROWS + BM - 1) / BM);
            gemm_bt<0><<<grid, blk, 0, stream>>>(
                u_ws, x_proj_W + (size_t)i * XPROJ_N * D_INNER, nullptr, nullptr,
                xdbl_ws, MROWS, XPROJ_N, D_INNER, D_INNER, XPROJ_N);
        }
        // delta = softplus(x_dbl[:, :24] @ dt_proj_W[i].T + dt_proj_b[i])
        {
            dim3 grid((D_INNER + BN - 1) / BN, (MROWS + BM - 1) / BM);
            gemm_bt<2><<<grid, blk, 0, stream>>>(
                xdbl_ws, dt_proj_W + (size_t)i * D_INNER * DT_RANK,
                dt_proj_b + i * D_INNER, nullptr,
                delta_ws, MROWS, D_INNER, DT_RANK, XPROJ_N, D_INNER);
        }
        // selective scan
        scan_k<<<B_ * (D_INNER / 16), blk, 0, stream>>>(
            delta_ws, u_ws, xdbl_ws, A_log + (size_t)i * D_INNER * N_STATE,
            Dp + i * D_INNER, y_ws);
        // y *= silu(res)
        gate_k<<<ew_blocks, blk, 0, stream>>>(y_ws, xz_ws);
        // x = y @ out_proj_W[i].T + x
        {
            dim3 grid((D_MODEL + BN - 1) / BN, (MROWS + BM - 1) / BM);
            gemm_bt<3><<<grid, blk, 0, stream>>>(
                y_ws, out_proj_W + (size_t)i * D_MODEL * D_INNER, nullptr, x_ws,
                x_ws, MROWS, D_MODEL, D_INNER, D_INNER, D_MODEL);
        }
    }

    // h = rmsnorm(x) * normf_W ; out = h @ head_W.T
    rmsnorm_k<<<MROWS, 128, 0, stream>>>(x_ws, normf_W, h_ws, D_MODEL);
    {
        dim3 grid((FEAT + BN - 1) / BN, (MROWS + BM - 1) / BM);
        gemm_bt<0><<<grid, blk, 0, stream>>>(
            h_ws, head_W, nullptr, nullptr, out, MROWS, FEAT, D_MODEL, D_MODEL, FEAT);
    }
}

// Round 3
// 1298.453 us; speedup vs baseline: 2.0703x; 2.0703x over previous
//
#include <hip/hip_runtime.h>
#include <math.h>

// Problem dims
#define B_ 4
#define L_ 512
#define MROWS 2048
#define D_MODEL 384
#define N_LAYER 4
#define D_INNER 768
#define N_STATE 16
#define DT_RANK 24
#define D_CONV 4
#define VOCAB 1544
#define FEAT 1536
#define XPROJ_N 56

__device__ __forceinline__ float softplus_f(float x) { return x > 20.f ? x : log1pf(expf(x)); }
__device__ __forceinline__ float silu_f(float x) { return x / (1.f + __expf(-x)); }

__device__ __forceinline__ float4 ld4_guard(const float* __restrict__ p, int k, int ke) {
    if (k + 3 < ke) return *(const float4*)(p + k);
    float4 r = make_float4(0.f, 0.f, 0.f, 0.f);
    if (k + 0 < ke) r.x = p[k + 0];
    if (k + 1 < ke) r.y = p[k + 1];
    if (k + 2 < ke) r.z = p[k + 2];
    if (k + 3 < ke) r.w = p[k + 3];
    return r;
}

// ---------------------------------------------------------------------------
// Tiled GEMM: C[m,n] (+)= sum_k A[m,k] * W[n,k]   (W row-major NxK, stride K)
// EPI: 0 none, 1 +bias (on z==0 split if ATOMIC), 2 softplus(x+bias)
// GATED: A[m,k] -> A[m,k] * silu(gate[m*ldg+k])
// ATOMIC: atomicAdd into C (split-K); else plain store.
// ---------------------------------------------------------------------------
#define BM 64
#define BN 64
#define BK 16

template <int EPI, bool GATED, bool ATOMIC>
__global__ __launch_bounds__(256) void gemm_bt(
    const float* __restrict__ A, const float* __restrict__ W,
    const float* __restrict__ bias, const float* __restrict__ gate,
    float* __restrict__ C, int M, int N, int K, int lda, int ldg, int ldc, int KC)
{
    __shared__ float As[BK][BM + 1];
    __shared__ float Ws[BK][BN + 1];
    const int t  = threadIdx.x;
    const int tx = t & 15;        // n-dim (4 cols each)
    const int ty = t >> 4;        // m-dim (4 rows each)
    const int m0 = blockIdx.y * BM;
    const int n0 = blockIdx.x * BN;
    const int ks = blockIdx.z * KC;
    const int ke = min(K, ks + KC);

    // staging indices: thread loads one float4 of A and one of W
    const int sr = t >> 2;            // 0..63 tile row
    const int sc = (t & 3) << 2;      // 0,4,8,12 k-offset
    const int gm = m0 + sr;
    const int gn = n0 + sr;

    float4 ra = make_float4(0.f, 0.f, 0.f, 0.f), rw = ra;

    auto prefetch = [&](int k0) {
        ra = make_float4(0.f, 0.f, 0.f, 0.f);
        rw = ra;
        if (gm < M) {
            ra = ld4_guard(A + (size_t)gm * lda, k0 + sc, ke);
            if (GATED) {
                float4 g = ld4_guard(gate + (size_t)gm * ldg, k0 + sc, ke);
                ra.x *= silu_f(g.x); ra.y *= silu_f(g.y);
                ra.z *= silu_f(g.z); ra.w *= silu_f(g.w);
            }
        }
        if (gn < N) rw = ld4_guard(W + (size_t)gn * (size_t)K, k0 + sc, ke);
    };

    prefetch(ks);

    float acc[4][4] = {};

    for (int k0 = ks; k0 < ke; k0 += BK) {
        __syncthreads();
        As[sc + 0][sr] = ra.x; As[sc + 1][sr] = ra.y;
        As[sc + 2][sr] = ra.z; As[sc + 3][sr] = ra.w;
        Ws[sc + 0][sr] = rw.x; Ws[sc + 1][sr] = rw.y;
        Ws[sc + 2][sr] = rw.z; Ws[sc + 3][sr] = rw.w;
        __syncthreads();
        if (k0 + BK < ke) prefetch(k0 + BK);   // loads in flight during compute
#pragma unroll
        for (int kk = 0; kk < BK; ++kk) {
            float a[4], b[4];
#pragma unroll
            for (int i = 0; i < 4; ++i) a[i] = As[kk][ty * 4 + i];
#pragma unroll
            for (int j = 0; j < 4; ++j) b[j] = Ws[kk][tx * 4 + j];
#pragma unroll
            for (int i = 0; i < 4; ++i)
#pragma unroll
                for (int j = 0; j < 4; ++j) acc[i][j] = fmaf(a[i], b[j], acc[i][j]);
        }
    }

#pragma unroll
    for (int i = 0; i < 4; ++i) {
        int om = m0 + ty * 4 + i;
        if (om >= M) continue;
        if (ATOMIC) {
#pragma unroll
            for (int j = 0; j < 4; ++j) {
                int on = n0 + tx * 4 + j;
                if (on >= N) continue;
                float v = acc[i][j];
                if (EPI == 1 && blockIdx.z == 0) v += bias[on];
                atomicAdd(&C[(size_t)om * ldc + on], v);
            }
        } else {
            int on0 = n0 + tx * 4;
            float v[4];
#pragma unroll
            for (int j = 0; j < 4; ++j) {
                v[j] = acc[i][j];
                if (EPI == 1 || EPI == 2) v[j] += bias[on0 + j < N ? on0 + j : 0];
                if (EPI == 2) v[j] = softplus_f(v[j]);
            }
            if (on0 + 3 < N) {
                *(float4*)(C + (size_t)om * ldc + on0) = make_float4(v[0], v[1], v[2], v[3]);
            } else {
#pragma unroll
                for (int j = 0; j < 4; ++j)
                    if (on0 + j < N) C[(size_t)om * ldc + on0 + j] = v[j];
            }
        }
    }
}

// ---------------------------------------------------------------------------
// RMSNorm (D = 384)
// ---------------------------------------------------------------------------
__global__ __launch_bounds__(128) void rmsnorm_k(
    const float* __restrict__ x, const float* __restrict__ w,
    float* __restrict__ out, int D)
{
    const int m = blockIdx.x;
    const float* xr = x + (size_t)m * D;
    float s = 0.f;
    for (int i = threadIdx.x; i < D; i += 128) { float v = xr[i]; s += v * v; }
#pragma unroll
    for (int off = 32; off > 0; off >>= 1) s += __shfl_down(s, off, 64);
    __shared__ float red[2];
    if ((threadIdx.x & 63) == 0) red[threadIdx.x >> 6] = s;
    __syncthreads();
    float scale = rsqrtf((red[0] + red[1]) / (float)D + 1e-5f);
    for (int i = threadIdx.x; i < D; i += 128)
        out[(size_t)m * D + i] = xr[i] * scale * w[i];
}

// ---------------------------------------------------------------------------
// Depthwise causal conv (width 4) + bias + SiLU, float4 over channels.
// ---------------------------------------------------------------------------
__global__ __launch_bounds__(256) void conv_silu_k(
    const float* __restrict__ xz, const float* __restrict__ w,
    const float* __restrict__ cb, float* __restrict__ u)
{
    int idx = blockIdx.x * 256 + threadIdx.x;
    if (idx >= MROWS * (D_INNER / 4)) return;
    int dq = idx % (D_INNER / 4);
    int m  = idx / (D_INNER / 4);
    int d0 = dq * 4;
    int b = m / L_, l = m % L_;
    float4 wq[4];
#pragma unroll
    for (int j = 0; j < 4; ++j) wq[j] = *(const float4*)(w + (d0 + j) * D_CONV);
    float acc[4];
#pragma unroll
    for (int j = 0; j < 4; ++j) acc[j] = cb[d0 + j];
#pragma unroll
    for (int tt = 0; tt < 4; ++tt) {
        int ll = l - 3 + tt;
        if (ll >= 0) {
            float4 xv = *(const float4*)(xz + (size_t)(b * L_ + ll) * (2 * D_INNER) + d0);
            acc[0] = fmaf(xv.x, ((const float*)&wq[0])[tt], acc[0]);
            acc[1] = fmaf(xv.y, ((const float*)&wq[1])[tt], acc[1]);
            acc[2] = fmaf(xv.z, ((const float*)&wq[2])[tt], acc[2]);
            acc[3] = fmaf(xv.w, ((const float*)&wq[3])[tt], acc[3]);
        }
    }
    float4 o = make_float4(silu_f(acc[0]), silu_f(acc[1]), silu_f(acc[2]), silu_f(acc[3]));
    *(float4*)(u + (size_t)m * D_INNER + d0) = o;
}

// ---------------------------------------------------------------------------
// Selective scan, LDS-chunked (64 steps). Block = 16 d x 16 n.
// ---------------------------------------------------------------------------
#define SCH 64
__global__ __launch_bounds__(256) void scan_k(
    const float* __restrict__ delta, const float* __restrict__ u,
    const float* __restrict__ xdbl, const float* __restrict__ A_log,
    const float* __restrict__ Dp, float* __restrict__ y)
{
    __shared__ float sd[SCH][16], su[SCH][16], sB[SCH][16], sC[SCH][16];
    const int t  = threadIdx.x;
    const int n  = t & 15;
    const int dl = t >> 4;
    const int b  = blockIdx.x / (D_INNER / 16);
    const int dg = blockIdx.x % (D_INNER / 16);
    const int d  = dg * 16 + dl;

    const float Av = -expf(A_log[d * N_STATE + n]);
    const float Dd = Dp[d];
    const int lr = t >> 2;          // 0..63 chunk row
    const int lc = (t & 3) << 2;    // 0,4,8,12
    float h = 0.f;

    for (int c0 = 0; c0 < L_; c0 += SCH) {
        const size_t mrow = (size_t)b * L_ + c0 + lr;
        const float4 vd = *(const float4*)(delta + mrow * D_INNER + dg * 16 + lc);
        const float4 vu = *(const float4*)(u     + mrow * D_INNER + dg * 16 + lc);
        const float4 vB = *(const float4*)(xdbl  + mrow * XPROJ_N + DT_RANK + lc);
        const float4 vC = *(const float4*)(xdbl  + mrow * XPROJ_N + DT_RANK + N_STATE + lc);
        __syncthreads();
        *(float4*)&sd[lr][lc] = vd;
        *(float4*)&su[lr][lc] = vu;
        *(float4*)&sB[lr][lc] = vB;
        *(float4*)&sC[lr][lc] = vC;
        __syncthreads();
#pragma unroll 8
        for (int j = 0; j < SCH; ++j) {
            float dv = sd[j][dl];
            float uv = su[j][dl];
            float e  = __expf(dv * Av);
            float c  = dv * uv * sB[j][n];
            h = fmaf(e, h, c);
            float p = h * sC[j][n];
            p += __shfl_xor(p, 1, 16);
            p += __shfl_xor(p, 2, 16);
            p += __shfl_xor(p, 4, 16);
            p += __shfl_xor(p, 8, 16);
            if (n == 0) y[((size_t)b * L_ + c0 + j) * D_INNER + d] = fmaf(uv, Dd, p);
        }
    }
}

// ---------------------------------------------------------------------------
extern "C" void kernel_launch(void* const* d_in, const int* in_sizes, int n_in,
                              void* d_out, int out_size, void* d_ws, size_t ws_size,
                              hipStream_t stream)
{
    const float* input_ids = (const float*)d_in[0];
    const float* fc_W      = (const float*)d_in[1];
    const float* fc_b      = (const float*)d_in[2];
    const float* in_proj_W = (const float*)d_in[3];
    const float* conv_W    = (const float*)d_in[4];
    const float* conv_b    = (const float*)d_in[5];
    const float* x_proj_W  = (const float*)d_in[6];
    const float* dt_proj_W = (const float*)d_in[7];
    const float* dt_proj_b = (const float*)d_in[8];
    const float* A_log     = (const float*)d_in[9];
    const float* Dp        = (const float*)d_in[10];
    const float* out_proj_W= (const float*)d_in[11];
    const float* norm_W    = (const float*)d_in[12];
    const float* normf_W   = (const float*)d_in[13];
    const float* head_W    = (const float*)d_in[14];
    float* out = (float*)d_out;

    float* ws       = (float*)d_ws;
    float* x_ws     = ws;                                    // M*384
    float* h_ws     = x_ws    + (size_t)MROWS * D_MODEL;     // M*384
    float* xz_ws    = h_ws    + (size_t)MROWS * D_MODEL;     // M*1536
    float* u_ws     = xz_ws   + (size_t)MROWS * 2 * D_INNER; // M*768
    float* xdbl_ws  = u_ws    + (size_t)MROWS * D_INNER;     // M*56
    float* delta_ws = xdbl_ws + (size_t)MROWS * XPROJ_N;     // M*768
    float* y_ws     = delta_ws+ (size_t)MROWS * D_INNER;     // M*768

    const dim3 blk(256);

    // x = input_ids @ fc_W.T + fc_b   (split-K=4, atomic into zeroed x)
    hipMemsetAsync(x_ws, 0, (size_t)MROWS * D_MODEL * sizeof(float), stream);
    gemm_bt<1, false, true><<<dim3(D_MODEL / BN, MROWS / BM, 4), blk, 0, stream>>>(
        input_ids, fc_W, fc_b, nullptr, x_ws,
        MROWS, D_MODEL, VOCAB, VOCAB, 0, D_MODEL, 388);

    for (int i = 0; i < N_LAYER; ++i) {
        rmsnorm_k<<<MROWS, 128, 0, stream>>>(x_ws, norm_W + i * D_MODEL, h_ws, D_MODEL);

        // xz = h @ in_proj_W[i].T  (768 blocks)
        gemm_bt<0, false, false><<<dim3(2 * D_INNER / BN, MROWS / BM, 1), blk, 0, stream>>>(
            h_ws, in_proj_W + (size_t)i * 2 * D_INNER * D_MODEL, nullptr, nullptr,
            xz_ws, MROWS, 2 * D_INNER, D_MODEL, D_MODEL, 0, 2 * D_INNER, D_MODEL);

        // u = silu(conv(xz[:, :768]) + conv_b)
        conv_silu_k<<<(MROWS * (D_INNER / 4) + 255) / 256, blk, 0, stream>>>(
            xz_ws, conv_W + (size_t)i * D_INNER * D_CONV, conv_b + i * D_INNER, u_ws);

        // x_dbl = u @ x_proj_W[i].T  (split-K=6, atomic into zeroed xdbl)
        hipMemsetAsync(xdbl_ws, 0, (size_t)MROWS * XPROJ_N * sizeof(float), stream);
        gemm_bt<0, false, true><<<dim3(1, MROWS / BM, 6), blk, 0, stream>>>(
            u_ws, x_proj_W + (size_t)i * XPROJ_N * D_INNER, nullptr, nullptr,
            xdbl_ws, MROWS, XPROJ_N, D_INNER, D_INNER, 0, XPROJ_N, 128);

        // delta = softplus(x_dbl[:, :24] @ dt_proj_W[i].T + dt_proj_b[i])
        gemm_bt<2, false, false><<<dim3(D_INNER / BN, MROWS / BM, 1), blk, 0, stream>>>(
            xdbl_ws, dt_proj_W + (size_t)i * D_INNER * DT_RANK,
            dt_proj_b + i * D_INNER, nullptr,
            delta_ws, MROWS, D_INNER, DT_RANK, XPROJ_N, 0, D_INNER, DT_RANK);

        // selective scan
        scan_k<<<B_ * (D_INNER / 16), blk, 0, stream>>>(
            delta_ws, u_ws, xdbl_ws, A_log + (size_t)i * D_INNER * N_STATE,
            Dp + i * D_INNER, y_ws);

        // x += (y * silu(res)) @ out_proj_W[i].T   (gated A, split-K=4, atomic residual)
        gemm_bt<0, true, true><<<dim3(D_MODEL / BN, MROWS / BM, 4), blk, 0, stream>>>(
            y_ws, out_proj_W + (size_t)i * D_MODEL * D_INNER, nullptr, xz_ws + D_INNER,
            x_ws, MROWS, D_MODEL, D_INNER, D_INNER, 2 * D_INNER, D_MODEL, 192);
    }

    rmsnorm_k<<<MROWS, 128, 0, stream>>>(x_ws, normf_W, h_ws, D_MODEL);
    // out = h @ head_W.T  (768 blocks)
    gemm_bt<0, false, false><<<dim3(FEAT / BN, MROWS / BM, 1), blk, 0, stream>>>(
        h_ws, head_W, nullptr, nullptr, out, MROWS, FEAT, D_MODEL, D_MODEL, 0, FEAT, D_MODEL);
}

// Round 4
// 1175.667 us; speedup vs baseline: 2.2866x; 1.1044x over previous
//
#include <hip/hip_runtime.h>
#include <math.h>

// Problem dims
#define B_ 4
#define L_ 512
#define MROWS 2048
#define D_MODEL 384
#define N_LAYER 4
#define D_INNER 768
#define N_STATE 16
#define DT_RANK 24
#define D_CONV 4
#define VOCAB 1544
#define FEAT 1536
#define XPROJ_N 56

__device__ __forceinline__ float softplus_f(float x) { return x > 20.f ? x : log1pf(expf(x)); }
__device__ __forceinline__ float silu_f(float x) { return x / (1.f + __expf(-x)); }

// DPP row-rotate add: returns x + (x rotated by N within each 16-lane row).
// ctrl 0x120+N = row_ror:N. Rotations by 8,4,2,1 compose to a full row-sum.
template <int CTRL>
__device__ __forceinline__ float dpp_radd(float x) {
    int r = __builtin_amdgcn_update_dpp(0, __float_as_int(x), CTRL, 0xf, 0xf, true);
    return x + __int_as_float(r);
}

__device__ __forceinline__ float4 ld4_guard(const float* __restrict__ p, int k, int ke) {
    if (k + 3 < ke) return *(const float4*)(p + k);
    float4 r = make_float4(0.f, 0.f, 0.f, 0.f);
    if (k + 0 < ke) r.x = p[k + 0];
    if (k + 1 < ke) r.y = p[k + 1];
    if (k + 2 < ke) r.z = p[k + 2];
    if (k + 3 < ke) r.w = p[k + 3];
    return r;
}

// ---------------------------------------------------------------------------
// Tiled GEMM: C[m,n] (+)= sum_k A[m,k] * W[n,k]   (W row-major NxK, stride K)
// EPI: 0 none, 1 +bias (z==0 split only if ATOMIC), 2 softplus(x+bias)
// GATED: A[m,k] *= silu(gate[m*ldg+k]);  ATOMIC: atomicAdd into C (split-K)
// Double-buffered LDS, one barrier per K-step, prefetch ahead of compute.
// ---------------------------------------------------------------------------
#define BM 64
#define BN 64
#define BK 16

template <int EPI, bool GATED, bool ATOMIC>
__global__ __launch_bounds__(256) void gemm_bt(
    const float* __restrict__ A, const float* __restrict__ W,
    const float* __restrict__ bias, const float* __restrict__ gate,
    float* __restrict__ C, int M, int N, int K, int lda, int ldg, int ldc, int KC)
{
    __shared__ float As[2][BK][BM + 1];
    __shared__ float Ws[2][BK][BN + 1];
    const int t  = threadIdx.x;
    const int tx = t & 15;        // n-dim (4 cols each)
    const int ty = t >> 4;        // m-dim (4 rows each)
    const int m0 = blockIdx.y * BM;
    const int n0 = blockIdx.x * BN;
    const int ks = blockIdx.z * KC;
    const int ke = min(K, ks + KC);

    const int sr = t >> 2;            // 0..63 tile row
    const int sc = (t & 3) << 2;      // 0,4,8,12 k-offset
    const int gm = m0 + sr;
    const int gn = n0 + sr;

    float4 ra = make_float4(0.f, 0.f, 0.f, 0.f), rw = ra;

    auto prefetch = [&](int k0) {
        ra = make_float4(0.f, 0.f, 0.f, 0.f);
        rw = ra;
        if (gm < M) {
            ra = ld4_guard(A + (size_t)gm * lda, k0 + sc, ke);
            if (GATED) {
                float4 g = ld4_guard(gate + (size_t)gm * ldg, k0 + sc, ke);
                ra.x *= silu_f(g.x); ra.y *= silu_f(g.y);
                ra.z *= silu_f(g.z); ra.w *= silu_f(g.w);
            }
        }
        if (gn < N) rw = ld4_guard(W + (size_t)gn * (size_t)K, k0 + sc, ke);
    };

    auto stage = [&](int p) {
        As[p][sc + 0][sr] = ra.x; As[p][sc + 1][sr] = ra.y;
        As[p][sc + 2][sr] = ra.z; As[p][sc + 3][sr] = ra.w;
        Ws[p][sc + 0][sr] = rw.x; Ws[p][sc + 1][sr] = rw.y;
        Ws[p][sc + 2][sr] = rw.z; Ws[p][sc + 3][sr] = rw.w;
    };

    prefetch(ks);
    stage(0);
    __syncthreads();

    float acc[4][4] = {};
    int p = 0;

    for (int k0 = ks; k0 < ke; k0 += BK) {
        const bool more = (k0 + BK < ke);
        if (more) prefetch(k0 + BK);          // global loads in flight during compute
#pragma unroll
        for (int kk = 0; kk < BK; ++kk) {
            float a[4], b[4];
#pragma unroll
            for (int i = 0; i < 4; ++i) a[i] = As[p][kk][ty * 4 + i];
#pragma unroll
            for (int j = 0; j < 4; ++j) b[j] = Ws[p][kk][tx * 4 + j];
#pragma unroll
            for (int i = 0; i < 4; ++i)
#pragma unroll
                for (int j = 0; j < 4; ++j) acc[i][j] = fmaf(a[i], b[j], acc[i][j]);
        }
        if (more) {
            stage(p ^ 1);                     // buf p^1 not read until after barrier
            __syncthreads();
            p ^= 1;
        }
    }

#pragma unroll
    for (int i = 0; i < 4; ++i) {
        int om = m0 + ty * 4 + i;
        if (om >= M) continue;
        if (ATOMIC) {
#pragma unroll
            for (int j = 0; j < 4; ++j) {
                int on = n0 + tx * 4 + j;
                if (on >= N) continue;
                float v = acc[i][j];
                if (EPI == 1 && blockIdx.z == 0) v += bias[on];
                atomicAdd(&C[(size_t)om * ldc + on], v);
            }
        } else {
            int on0 = n0 + tx * 4;
            float v[4];
#pragma unroll
            for (int j = 0; j < 4; ++j) {
                v[j] = acc[i][j];
                if (EPI == 1 || EPI == 2) v[j] += bias[on0 + j < N ? on0 + j : 0];
                if (EPI == 2) v[j] = softplus_f(v[j]);
            }
            if (on0 + 3 < N) {
                *(float4*)(C + (size_t)om * ldc + on0) = make_float4(v[0], v[1], v[2], v[3]);
            } else {
#pragma unroll
                for (int j = 0; j < 4; ++j)
                    if (on0 + j < N) C[(size_t)om * ldc + on0 + j] = v[j];
            }
        }
    }
}

// ---------------------------------------------------------------------------
// RMSNorm (D = 384)
// ---------------------------------------------------------------------------
__global__ __launch_bounds__(128) void rmsnorm_k(
    const float* __restrict__ x, const float* __restrict__ w,
    float* __restrict__ out, int D)
{
    const int m = blockIdx.x;
    const float* xr = x + (size_t)m * D;
    float s = 0.f;
    for (int i = threadIdx.x; i < D; i += 128) { float v = xr[i]; s += v * v; }
#pragma unroll
    for (int off = 32; off > 0; off >>= 1) s += __shfl_down(s, off, 64);
    __shared__ float red[2];
    if ((threadIdx.x & 63) == 0) red[threadIdx.x >> 6] = s;
    __syncthreads();
    float scale = rsqrtf((red[0] + red[1]) / (float)D + 1e-5f);
    for (int i = threadIdx.x; i < D; i += 128)
        out[(size_t)m * D + i] = xr[i] * scale * w[i];
}

// ---------------------------------------------------------------------------
// Depthwise causal conv (width 4) + bias + SiLU, float4 over channels.
// ---------------------------------------------------------------------------
__global__ __launch_bounds__(256) void conv_silu_k(
    const float* __restrict__ xz, const float* __restrict__ w,
    const float* __restrict__ cb, float* __restrict__ u)
{
    int idx = blockIdx.x * 256 + threadIdx.x;
    if (idx >= MROWS * (D_INNER / 4)) return;
    int dq = idx % (D_INNER / 4);
    int m  = idx / (D_INNER / 4);
    int d0 = dq * 4;
    int b = m / L_, l = m % L_;
    float4 wq[4];
#pragma unroll
    for (int j = 0; j < 4; ++j) wq[j] = *(const float4*)(w + (d0 + j) * D_CONV);
    float acc[4];
#pragma unroll
    for (int j = 0; j < 4; ++j) acc[j] = cb[d0 + j];
#pragma unroll
    for (int tt = 0; tt < 4; ++tt) {
        int ll = l - 3 + tt;
        if (ll >= 0) {
            float4 xv = *(const float4*)(xz + (size_t)(b * L_ + ll) * (2 * D_INNER) + d0);
            acc[0] = fmaf(xv.x, ((const float*)&wq[0])[tt], acc[0]);
            acc[1] = fmaf(xv.y, ((const float*)&wq[1])[tt], acc[1]);
            acc[2] = fmaf(xv.z, ((const float*)&wq[2])[tt], acc[2]);
            acc[3] = fmaf(xv.w, ((const float*)&wq[3])[tt], acc[3]);
        }
    }
    float4 o = make_float4(silu_f(acc[0]), silu_f(acc[1]), silu_f(acc[2]), silu_f(acc[3]));
    *(float4*)(u + (size_t)m * D_INNER + d0) = o;
}

// ---------------------------------------------------------------------------
// Selective scan, LDS-chunked (64 steps). Block = 16 d x 16 n.
// Reduction over the 16 states uses DPP row rotations (VALU), not LDS perms.
// ---------------------------------------------------------------------------
#define SCH 64
__global__ __launch_bounds__(256) void scan_k(
    const float* __restrict__ delta, const float* __restrict__ u,
    const float* __restrict__ xdbl, const float* __restrict__ A_log,
    const float* __restrict__ Dp, float* __restrict__ y)
{
    __shared__ float sd[SCH][16], su[SCH][16], sB[SCH][16], sC[SCH][16];
    const int t  = threadIdx.x;
    const int n  = t & 15;
    const int dl = t >> 4;
    const int b  = blockIdx.x / (D_INNER / 16);
    const int dg = blockIdx.x % (D_INNER / 16);
    const int d  = dg * 16 + dl;

    const float Av = -expf(A_log[d * N_STATE + n]);
    const float Dd = Dp[d];
    const int lr = t >> 2;          // 0..63 chunk row
    const int lc = (t & 3) << 2;    // 0,4,8,12
    float h = 0.f;

    for (int c0 = 0; c0 < L_; c0 += SCH) {
        const size_t mrow = (size_t)b * L_ + c0 + lr;
        const float4 vd = *(const float4*)(delta + mrow * D_INNER + dg * 16 + lc);
        const float4 vu = *(const float4*)(u     + mrow * D_INNER + dg * 16 + lc);
        const float4 vB = *(const float4*)(xdbl  + mrow * XPROJ_N + DT_RANK + lc);
        const float4 vC = *(const float4*)(xdbl  + mrow * XPROJ_N + DT_RANK + N_STATE + lc);
        __syncthreads();
        *(float4*)&sd[lr][lc] = vd;
        *(float4*)&su[lr][lc] = vu;
        *(float4*)&sB[lr][lc] = vB;
        *(float4*)&sC[lr][lc] = vC;
        __syncthreads();
#pragma unroll 8
        for (int j = 0; j < SCH; ++j) {
            float dv = sd[j][dl];
            float uv = su[j][dl];
            float e  = __expf(dv * Av);
            float c  = dv * uv * sB[j][n];
            h = fmaf(e, h, c);
            float p = h * sC[j][n];
            p = dpp_radd<0x128>(p);   // + ror 8
            p = dpp_radd<0x124>(p);   // + ror 4
            p = dpp_radd<0x122>(p);   // + ror 2
            p = dpp_radd<0x121>(p);   // + ror 1 -> full 16-state sum in every lane
            if (n == 0) y[((size_t)b * L_ + c0 + j) * D_INNER + d] = fmaf(uv, Dd, p);
        }
    }
}

// ---------------------------------------------------------------------------
extern "C" void kernel_launch(void* const* d_in, const int* in_sizes, int n_in,
                              void* d_out, int out_size, void* d_ws, size_t ws_size,
                              hipStream_t stream)
{
    const float* input_ids = (const float*)d_in[0];
    const float* fc_W      = (const float*)d_in[1];
    const float* fc_b      = (const float*)d_in[2];
    const float* in_proj_W = (const float*)d_in[3];
    const float* conv_W    = (const float*)d_in[4];
    const float* conv_b    = (const float*)d_in[5];
    const float* x_proj_W  = (const float*)d_in[6];
    const float* dt_proj_W = (const float*)d_in[7];
    const float* dt_proj_b = (const float*)d_in[8];
    const float* A_log     = (const float*)d_in[9];
    const float* Dp        = (const float*)d_in[10];
    const float* out_proj_W= (const float*)d_in[11];
    const float* norm_W    = (const float*)d_in[12];
    const float* normf_W   = (const float*)d_in[13];
    const float* head_W    = (const float*)d_in[14];
    float* out = (float*)d_out;

    float* ws       = (float*)d_ws;
    float* x_ws     = ws;                                    // M*384
    float* h_ws     = x_ws    + (size_t)MROWS * D_MODEL;     // M*384
    float* xz_ws    = h_ws    + (size_t)MROWS * D_MODEL;     // M*1536
    float* u_ws     = xz_ws   + (size_t)MROWS * 2 * D_INNER; // M*768
    float* xdbl_ws  = u_ws    + (size_t)MROWS * D_INNER;     // M*56
    float* delta_ws = xdbl_ws + (size_t)MROWS * XPROJ_N;     // M*768
    float* y_ws     = delta_ws+ (size_t)MROWS * D_INNER;     // M*768

    const dim3 blk(256);

    // x = input_ids @ fc_W.T + fc_b   (split-K=4, atomic into zeroed x)
    hipMemsetAsync(x_ws, 0, (size_t)MROWS * D_MODEL * sizeof(float), stream);
    gemm_bt<1, false, true><<<dim3(D_MODEL / BN, MROWS / BM, 4), blk, 0, stream>>>(
        input_ids, fc_W, fc_b, nullptr, x_ws,
        MROWS, D_MODEL, VOCAB, VOCAB, 0, D_MODEL, 388);

    for (int i = 0; i < N_LAYER; ++i) {
        rmsnorm_k<<<MROWS, 128, 0, stream>>>(x_ws, norm_W + i * D_MODEL, h_ws, D_MODEL);

        // xz = h @ in_proj_W[i].T  (768 blocks)
        gemm_bt<0, false, false><<<dim3(2 * D_INNER / BN, MROWS / BM, 1), blk, 0, stream>>>(
            h_ws, in_proj_W + (size_t)i * 2 * D_INNER * D_MODEL, nullptr, nullptr,
            xz_ws, MROWS, 2 * D_INNER, D_MODEL, D_MODEL, 0, 2 * D_INNER, D_MODEL);

        // u = silu(conv(xz[:, :768]) + conv_b)
        conv_silu_k<<<(MROWS * (D_INNER / 4) + 255) / 256, blk, 0, stream>>>(
            xz_ws, conv_W + (size_t)i * D_INNER * D_CONV, conv_b + i * D_INNER, u_ws);

        // x_dbl = u @ x_proj_W[i].T  (split-K=6, atomic into zeroed xdbl)
        hipMemsetAsync(xdbl_ws, 0, (size_t)MROWS * XPROJ_N * sizeof(float), stream);
        gemm_bt<0, false, true><<<dim3(1, MROWS / BM, 6), blk, 0, stream>>>(
            u_ws, x_proj_W + (size_t)i * XPROJ_N * D_INNER, nullptr, nullptr,
            xdbl_ws, MROWS, XPROJ_N, D_INNER, D_INNER, 0, XPROJ_N, 128);

        // delta = softplus(x_dbl[:, :24] @ dt_proj_W[i].T + dt_proj_b[i])
        gemm_bt<2, false, false><<<dim3(D_INNER / BN, MROWS / BM, 1), blk, 0, stream>>>(
            xdbl_ws, dt_proj_W + (size_t)i * D_INNER * DT_RANK,
            dt_proj_b + i * D_INNER, nullptr,
            delta_ws, MROWS, D_INNER, DT_RANK, XPROJ_N, 0, D_INNER, DT_RANK);

        // selective scan
        scan_k<<<B_ * (D_INNER / 16), blk, 0, stream>>>(
            delta_ws, u_ws, xdbl_ws, A_log + (size_t)i * D_INNER * N_STATE,
            Dp + i * D_INNER, y_ws);

        // x += (y * silu(res)) @ out_proj_W[i].T   (gated A, split-K=2, atomic residual)
        gemm_bt<0, true, true><<<dim3(D_MODEL / BN, MROWS / BM, 2), blk, 0, stream>>>(
            y_ws, out_proj_W + (size_t)i * D_MODEL * D_INNER, nullptr, xz_ws + D_INNER,
            x_ws, MROWS, D_MODEL, D_INNER, D_INNER, 2 * D_INNER, D_MODEL, 384);
    }

    rmsnorm_k<<<MROWS, 128, 0, stream>>>(x_ws, normf_W, h_ws, D_MODEL);
    // out = h @ head_W.T  (768 blocks)
    gemm_bt<0, false, false><<<dim3(FEAT / BN, MROWS / BM, 1), blk, 0, stream>>>(
        h_ws, head_W, nullptr, nullptr, out, MROWS, FEAT, D_MODEL, D_MODEL, 0, FEAT, D_MODEL);
}